// Round 8
// baseline (115.855 us; speedup 1.0000x reference)
//
#include <hip/hip_runtime.h>

#define B_   512
#define T_   365
#define C_   10
#define P_   64
#define K_   3650   // T*C
#define K2_  1825   // K_ in float2
#define XROW 3712   // xm LDS row stride (floats) = 928 float4, 16B aligned

// d_out flat offsets (floats), in reference return order
#define OFF_OUT0 0u          // output_seq [B,T,C]
#define OFF_IN   1868800u    // input_seq  [B,T,C]
#define OFF_DIST 3737600u    // distances  [B,P]
#define OFF_IDX  3770368u    // indices    [B]
#define OFF_LAB  3770880u    // label      [B]
#define OFF_MASK 3771392u    // mask       [B,T]

// ws layout (floats): [0,512) x2m per sample ; [512, 512+365*64) sp[t][p]
#define WS_X2 0
#define WS_SP 512

// Grid: 512 blocks = 128 batch-groups (4 rows) x 4 proto-quarters (16
// protos). 512 threads = 8 waves; wave w owns protos q*16+2w, +1 over all
// 4 rows. Proto L2 traffic = 512 x 234KB = 120 MB; XCD = blk%8 and
// quarter = blk&3 => each XCD touches one 234KB quarter -> L2-resident.
// Dot-form, no in-loop mask: d'[b][p] = -2*sum_k xm[k]*p[k]; the c-term
// (sum_t m*sp) and x2m are added by argmin_kernel via ws. K-loop: 14 f4
// iters (floats [0,3584)) + guarded f2 tail (f2 [1792,1825)) -> no OOB.
__global__ __launch_bounds__(512, 4) void dist_kernel(
    const float* __restrict__ x, const float* __restrict__ mask,
    const float* __restrict__ protos, float* __restrict__ out,
    float* __restrict__ ws)
{
    __shared__ float xm[4][XROW];    // masked x rows (float4-aligned stride)
    __shared__ float mrow[4][368];   // mask rows
    __shared__ float r2[8][4];       // x2 wave partials

    const int tid  = threadIdx.x;
    const int lane = tid & 63;
    const int wv   = tid >> 6;           // 0..7
    const int g    = blockIdx.x >> 2;    // batch group
    const int q    = blockIdx.x & 3;     // proto quarter
    const int b0   = g * 4;

    // ---- sp slice: 46 entries per block -> ws[WS_SP + t*64 + p] ----
    if (tid < 46) {
        int j = blockIdx.x * 46 + tid;
        if (j < T_ * P_) {
            int t = j >> 6, p = j & 63;
            const float* pp = protos + (size_t)p * K_ + t * C_;
            float s = 0.f;
#pragma unroll
            for (int c = 0; c < C_; ++c) s = fmaf(pp[c], pp[c], s);
            ws[WS_SP + j] = s;
        }
    }

    // ---- stage mask rows (+ echo from quarter 0) ----
    for (int j = tid; j < 4 * 368; j += 512) {
        const int r = j >> 9 ? 0 : 0;  (void)r;
        const int rr = j / 368;
        const int t  = j - rr * 368;
        float m = 0.f;
        if (t < T_) {
            m = mask[(size_t)(b0 + rr) * T_ + t];
            if (q == 0) out[OFF_MASK + (size_t)(b0 + rr) * T_ + t] = m;
        }
        mrow[rr][t] = m;
    }
    __syncthreads();

    // ---- stage masked x rows (float2) + fused input echo + x2 partials ----
    float s2[4] = {0.f, 0.f, 0.f, 0.f};
#pragma unroll
    for (int r = 0; r < 4; ++r) {
        const float2* xr = (const float2*)(x + (size_t)(b0 + r) * K_);
        float*        eb = out + OFF_IN + (size_t)(b0 + r) * K_;
        float2*       sx = (float2*)&xm[r][0];
        for (int i2 = tid; i2 < K2_; i2 += 512) {
            float2 v = xr[i2];
            if (q == 0) {   // nontemporal: don't evict protos from L2
                __builtin_nontemporal_store(v.x, eb + 2 * i2);
                __builtin_nontemporal_store(v.y, eb + 2 * i2 + 1);
            }
            const float m = mrow[r][(unsigned)i2 / 5u];
            v.x *= m; v.y *= m;
            sx[i2] = v;
            s2[r] = fmaf(v.x, v.x, fmaf(v.y, v.y, s2[r]));
        }
    }
#pragma unroll
    for (int r = 0; r < 4; ++r) {
        float v = s2[r];
        for (int off = 32; off; off >>= 1) v += __shfl_down(v, off);
        if (lane == 0) r2[wv][r] = v;
    }
    __syncthreads();
    if (q == 0 && tid < 4) {
        float s = 0.f;
#pragma unroll
        for (int w = 0; w < 8; ++w) s += r2[w][tid];
        ws[WS_X2 + b0 + tid] = s;
    }

    // ---- main K-loop: 2 protos x 4 rows per wave ----
    const int pidx = q * 16 + wv * 2;
    const float2* pr0 = (const float2*)(protos + (size_t)pidx * K_);
    const float2* pr1 = (const float2*)(protos + (size_t)(pidx + 1) * K_);

    float2 a0[4], a1[4];
#pragma unroll
    for (int r = 0; r < 4; ++r) { a0[r] = {0.f, 0.f}; a1[r] = {0.f, 0.f}; }

#pragma unroll 2
    for (int it = 0; it < 14; ++it) {
        const int i4 = it * 64 + lane;        // < 896 (floats [0,3584))
        const float2 p0l = pr0[2 * i4], p0h = pr0[2 * i4 + 1];
        const float2 p1l = pr1[2 * i4], p1h = pr1[2 * i4 + 1];
#pragma unroll
        for (int r = 0; r < 4; ++r) {
            const float4 u = ((const float4*)&xm[r][0])[i4];
            a0[r].x = fmaf(u.x, p0l.x, a0[r].x);
            a0[r].y = fmaf(u.y, p0l.y, a0[r].y);
            a0[r].x = fmaf(u.z, p0h.x, a0[r].x);
            a0[r].y = fmaf(u.w, p0h.y, a0[r].y);
            a1[r].x = fmaf(u.x, p1l.x, a1[r].x);
            a1[r].y = fmaf(u.y, p1l.y, a1[r].y);
            a1[r].x = fmaf(u.z, p1h.x, a1[r].x);
            a1[r].y = fmaf(u.w, p1h.y, a1[r].y);
        }
    }
    {   // f2 tail: f2 indices [1792, 1825)
        const int i2 = 1792 + lane;
        if (i2 < K2_) {
            const float2 pv0 = pr0[i2];
            const float2 pv1 = pr1[i2];
#pragma unroll
            for (int r = 0; r < 4; ++r) {
                const float2 u = ((const float2*)&xm[r][0])[i2];
                a0[r].x = fmaf(u.x, pv0.x, a0[r].x);
                a0[r].y = fmaf(u.y, pv0.y, a0[r].y);
                a1[r].x = fmaf(u.x, pv1.x, a1[r].x);
                a1[r].y = fmaf(u.y, pv1.y, a1[r].y);
            }
        }
    }

    // ---- reduce, write d' = -2*dot ----
#pragma unroll
    for (int r = 0; r < 4; ++r) {
        float v0 = a0[r].x + a0[r].y;
        float v1 = a1[r].x + a1[r].y;
        for (int off = 32; off; off >>= 1) {
            v0 += __shfl_down(v0, off);
            v1 += __shfl_down(v1, off);
        }
        if (lane == 0) {
            out[OFF_DIST + (size_t)(b0 + r) * P_ + pidx]     = -2.f * v0;
            out[OFF_DIST + (size_t)(b0 + r) * P_ + pidx + 1] = -2.f * v1;
        }
    }
}

// One block per sample: c-term from sp table, finalize distances
// (x2 + c + d'), argmin (first-occurrence tie-break), idx/label echo,
// gather selected proto row.
__global__ __launch_bounds__(256) void argmin_kernel(
    const float* __restrict__ mask, const int* __restrict__ label,
    const float* __restrict__ protos, const float* __restrict__ ws,
    float* __restrict__ out)
{
    __shared__ float c4[4][64];
    __shared__ int   sel;

    const int b    = blockIdx.x;
    const int tid  = threadIdx.x;
    const int part = tid >> 6;       // 0..3
    const int p    = tid & 63;

    // c[p] = sum_t m[b,t] * sp[t][p]   (sp reads coalesced across lanes)
    {
        const int t0  = part * 92;
        const int t1  = (part == 3) ? T_ : t0 + 92;
        const float* mb = mask + (size_t)b * T_;
        float acc = 0.f;
        for (int t = t0; t < t1; ++t)
            acc = fmaf(mb[t], ws[WS_SP + t * 64 + p], acc);
        c4[part][p] = acc;
    }
    __syncthreads();

    if (tid < 64) {
        const float c = c4[0][p] + c4[1][p] + c4[2][p] + c4[3][p];
        float v = ws[WS_X2 + b] + c + out[OFF_DIST + (size_t)b * P_ + p];
        out[OFF_DIST + (size_t)b * P_ + p] = v;
        int idx = p;
        for (int off = 32; off; off >>= 1) {
            float ov = __shfl_down(v, off);
            int   oi = __shfl_down(idx, off);
            if (ov < v || (ov == v && oi < idx)) { v = ov; idx = oi; }
        }
        if (p == 0) {
            sel = idx;
            out[OFF_IDX + b] = (float)idx;
            out[OFF_LAB + b] = (float)label[b];
        }
    }
    __syncthreads();

    // gather selected prototype row (nontemporal stores)
    const float2* src = (const float2*)(protos + (size_t)sel * K_);
    float* dst = out + OFF_OUT0 + (size_t)b * K_;
    for (int i2 = tid; i2 < K2_; i2 += 256) {
        const float2 v = src[i2];
        __builtin_nontemporal_store(v.x, dst + 2 * i2);
        __builtin_nontemporal_store(v.y, dst + 2 * i2 + 1);
    }
}

extern "C" void kernel_launch(void* const* d_in, const int* in_sizes, int n_in,
                              void* d_out, int out_size, void* d_ws, size_t ws_size,
                              hipStream_t stream) {
    const float* x      = (const float*)d_in[0];
    const float* mask   = (const float*)d_in[1];
    const int*   label  = (const int*)d_in[2];
    const float* protos = (const float*)d_in[3];
    float* out = (float*)d_out;
    float* ws  = (float*)d_ws;   // 95.5 KB used, rewritten every call

    dist_kernel<<<512, 512, 0, stream>>>(x, mask, protos, out, ws);
    argmin_kernel<<<B_, 256, 0, stream>>>(mask, label, protos, ws, out);
}